// Round 7
// baseline (128.978 us; speedup 1.0000x reference)
//
#include <hip/hip_runtime.h>

// Problem constants
#define B_SZ   8
#define S_LEN  1024
#define D_MOD  256
#define NHEADS 8
#define LOG2E  1.4426950408889634f
#define QSCALE_LOG2E 0.2550352766751165f   // (1/sqrt(32)) * log2(e)

typedef _Float16 f16x8 __attribute__((ext_vector_type(8)));
typedef _Float16 f16x4 __attribute__((ext_vector_type(4)));
typedef float    f32x4 __attribute__((ext_vector_type(4)));

// ---------------------------------------------------------------------------
// prep: blocks 0..31  : pack 4 fp32 W mats -> fragment-ordered fp16 wtp.
//        wtp[((mat*16+n16)*8+kk)*512 + lane*8 + j]
//          = W[kk*32 + (lane>>4)*8 + j][n16*16 + (lane&15)]
//       blocks 32..94 : bias C-init table
//        tab[((h*63+dy31)*3+e)*256 + lane*4 + r]
//          = rel[(dy31*63 + 16e + l16 - quad*4 - r + 15)*8 + h] * LOG2E
// ---------------------------------------------------------------------------
__global__ __launch_bounds__(256)
void prep_kernel(const float* __restrict__ Wq, const float* __restrict__ Wk,
                 const float* __restrict__ Wv, const float* __restrict__ Wo,
                 const float* __restrict__ rel,
                 _Float16* __restrict__ wtp, float* __restrict__ tab) {
    if (blockIdx.x < 32) {
        __shared__ _Float16 Wl[32 * 264];
        const int mi = blockIdx.x >> 3;
        const int k0 = (blockIdx.x & 7) << 5;
        const float* W = (mi == 0) ? Wq : (mi == 1) ? Wk : (mi == 2) ? Wv : Wo;
        {
            const int r  = threadIdx.x >> 3;
            const int c4 = (threadIdx.x & 7) * 4;
            const float* src = W + (size_t)(k0 + r) * 256 + c4;
#pragma unroll
            for (int g = 0; g < 8; ++g) {
                f32x4 v = *(const f32x4*)(src + g * 32);
                f16x4 o;
#pragma unroll
                for (int j = 0; j < 4; ++j) o[j] = (_Float16)v[j];
                *(f16x4*)(&Wl[r * 264 + c4 + g * 32]) = o;
            }
        }
        __syncthreads();
        const int n16 = threadIdx.x >> 4;
        const int l16 = threadIdx.x & 15;
        const int kk  = k0 >> 5;
#pragma unroll
        for (int quad = 0; quad < 4; ++quad) {
            f16x8 v;
#pragma unroll
            for (int j = 0; j < 8; ++j) v[j] = Wl[(quad * 8 + j) * 264 + n16 * 16 + l16];
            *(f16x8*)(wtp + (((size_t)(mi * 16 + n16) * 8 + kk) << 9) + (quad * 16 + l16) * 8) = v;
        }
        return;
    }
    __shared__ float rl[63 * 8];
    const int dy31 = blockIdx.x - 32;
    for (int f = threadIdx.x; f < 504; f += 256) rl[f] = rel[(size_t)dy31 * 504 + f];
    __syncthreads();
    const int h  = threadIdx.x >> 5;
    const int r5 = threadIdx.x & 31;
#pragma unroll
    for (int c = 0; c < 6; ++c) {
        const int oi   = r5 * 6 + c;       // 0..191
        const int e    = oi >> 6;
        const int lane = oi & 63;
        const int quad = lane >> 4, l16 = lane & 15;
        f32x4 v;
#pragma unroll
        for (int reg = 0; reg < 4; ++reg) {
            const int idx = 16 * e + l16 - quad * 4 - reg + 15;   // in [0,62]
            v[reg] = rl[idx * 8 + h] * LOG2E;
        }
        *(f32x4*)(tab + (((size_t)(h * 63 + dy31) * 3 + e) << 8) + lane * 4) = v;
    }
}

// ---------------------------------------------------------------------------
// QKV GEMM, folded N: 256 blocks = 128 m-tiles x z{0,1}. Block covers
// 64 act-rows x full N=256. A staged ONCE to LDS; B streamed frag-packed wtp.
// z=0: Q (swapped operands -> packed qs, scale+log2e folded).
// z=1: K (swapped -> packed ks) + V (normal -> packed vs) share the A tile.
// Epilogue: LDS transpose round-trips -> fragment-packed global stores.
// ---------------------------------------------------------------------------
__global__ __launch_bounds__(256)
void gemm_qkv_kernel(const float* __restrict__ in_q, const float* __restrict__ in_kv,
                     const _Float16* __restrict__ wtp,
                     const float* __restrict__ bq, const float* __restrict__ bk,
                     const float* __restrict__ bv,
                     _Float16* __restrict__ qs, _Float16* __restrict__ ks,
                     _Float16* __restrict__ vs) {
    __shared__ __align__(16) _Float16 Lds[256 * 72];   // 36.9 KB, reused 3 ways
    const int tid  = threadIdx.x;
    const int w    = tid >> 6;
    const int lane = tid & 63;
    const int quad = lane >> 4;
    const int l16  = lane & 15;
    const int m0 = blockIdx.x * 64, z = blockIdx.y;
    const int b = m0 >> 10, mloc = m0 & 1023;

    // stage A tile 64x256 fp32 -> fp16 (stride 264)
    {
        const int r  = tid >> 2;
        const int c4 = (tid & 3) * 4;
        const float* src = (z ? in_kv : in_q) + (size_t)(m0 + r) * 256 + c4;
        _Float16* dst = Lds + r * 264 + c4;
#pragma unroll
        for (int g = 0; g < 16; ++g) {
            f32x4 v = *(const f32x4*)(src + g * 16);
            f16x4 o;
#pragma unroll
            for (int j = 0; j < 4; ++j) o[j] = (_Float16)v[j];
            *(f16x4*)(dst + g * 16) = o;
        }
    }
    __syncthreads();

    f32x4 accA[4][4], accV[4][4];
#pragma unroll
    for (int i = 0; i < 4; ++i)
#pragma unroll
        for (int j = 0; j < 4; ++j) {
            accA[j][i] = (f32x4){0.f, 0.f, 0.f, 0.f};
            accV[j][i] = (f32x4){0.f, 0.f, 0.f, 0.f};
        }

    const int mA = z;   // Wq or Wk
#pragma unroll
    for (int kk = 0; kk < 8; ++kk) {
        const int k8 = kk * 32 + quad * 8;
        f16x8 a[4];
#pragma unroll
        for (int jj = 0; jj < 4; ++jj)
            a[jj] = *(const f16x8*)(Lds + (16 * jj + l16) * 264 + k8);
#pragma unroll
        for (int i = 0; i < 4; ++i) {
            f16x8 wa = *(const f16x8*)(wtp + (((size_t)(mA * 16 + w * 4 + i) * 8 + kk) << 9) + lane * 8);
#pragma unroll
            for (int jj = 0; jj < 4; ++jj)
                accA[jj][i] = __builtin_amdgcn_mfma_f32_16x16x32_f16(wa, a[jj], accA[jj][i], 0, 0, 0);
        }
        if (z == 1) {
#pragma unroll
            for (int i = 0; i < 4; ++i) {
                f16x8 wv = *(const f16x8*)(wtp + (((size_t)(32 + w * 4 + i) * 8 + kk) << 9) + lane * 8);
#pragma unroll
                for (int jj = 0; jj < 4; ++jj)
                    accV[jj][i] = __builtin_amdgcn_mfma_f32_16x16x32_f16(a[jj], wv, accV[jj][i], 0, 0, 0);
            }
        }
    }
    __syncthreads();

    // ---- Ta[act 64][hd 256] (stride 264): D^T of Q/K with bias+scale ----
    {
        const float* biasA = z ? bk : bq;
        const float  sc    = z ? 1.0f : QSCALE_LOG2E;
#pragma unroll
        for (int i = 0; i < 4; ++i) {
            f32x4 b4 = *(const f32x4*)(biasA + (w * 4 + i) * 16 + quad * 4);
#pragma unroll
            for (int jj = 0; jj < 4; ++jj) {
                f16x4 pk;
#pragma unroll
                for (int r = 0; r < 4; ++r) pk[r] = (_Float16)((accA[jj][i][r] + b4[r]) * sc);
                *(f16x4*)(Lds + (16 * jj + l16) * 264 + (w * 4 + i) * 16 + quad * 4) = pk;
            }
        }
    }
    __syncthreads();
    {
        _Float16* dstm = z ? ks : qs;
#pragma unroll
        for (int c = 0; c < 8; ++c) {
            const int sg  = w * 8 + c;          // 0..31
            const int tl  = sg >> 4, sub = (sg >> 3) & 1, h = sg & 7;
            f16x8 v = *(const f16x8*)(Lds + (tl * 32 + sub * 16 + l16) * 264 + h * 32 + quad * 8);
            const int tg = (mloc >> 5) + tl;
            *(f16x8*)(dstm + ((((size_t)(b * 8 + h) * 32 + tg) * 2 + sub) << 9) + lane * 8) = v;
        }
    }
    if (z == 1) {
        __syncthreads();
        // ---- Tb[hd 256][key 64] (stride 72): V^T with bias ----
#pragma unroll
        for (int i = 0; i < 4; ++i) {
            const float bvv = bv[(w * 4 + i) * 16 + l16];
#pragma unroll
            for (int jj = 0; jj < 4; ++jj) {
                f16x4 pk;
#pragma unroll
                for (int r = 0; r < 4; ++r) pk[r] = (_Float16)(accV[jj][i][r] + bvv);
                *(f16x4*)(Lds + ((w * 4 + i) * 16 + l16) * 72 + 16 * jj + quad * 4) = pk;
            }
        }
        __syncthreads();
#pragma unroll
        for (int c = 0; c < 8; ++c) {
            const int sg  = w * 8 + c;
            const int h = sg & 7, tl = (sg >> 3) & 1, sub = (sg >> 4) & 1;
            f16x8 v = *(const f16x8*)(Lds + (h * 32 + sub * 16 + l16) * 72 + tl * 32 + quad * 8);
            const int tg = (mloc >> 5) + tl;
            *(f16x8*)(vs + ((((size_t)(b * 8 + h) * 32 + tg) * 2 + sub) << 9) + lane * 8) = v;
        }
    }
}

// ---------------------------------------------------------------------------
// Output GEMM: zero-LDS, zero-barrier. A = xs (frag-packed by attn),
// B = wtp[mat 3] frag-packed stream. 512 blocks.
// ---------------------------------------------------------------------------
__global__ __launch_bounds__(256)
void gemm_out_kernel(const _Float16* __restrict__ xs, const _Float16* __restrict__ wtp,
                     const float* __restrict__ bo, float* __restrict__ out) {
    const int tid  = threadIdx.x;
    const int w    = tid >> 6;
    const int lane = tid & 63;
    const int quad = lane >> 4;
    const int l16  = lane & 15;
    const int bx = blockIdx.x, by = blockIdx.y;
    const int mt0  = bx * 4 + (w & 1) * 2;
    const int n16a = by * 4 + (w >> 1) * 2;

    f32x4 acc[2][2];
#pragma unroll
    for (int i = 0; i < 2; ++i)
#pragma unroll
        for (int j = 0; j < 2; ++j) acc[i][j] = (f32x4){0.f, 0.f, 0.f, 0.f};

#pragma unroll
    for (int kk = 0; kk < 8; ++kk) {
        f16x8 a0 = *(const f16x8*)(xs + (((size_t)(mt0 + 0) * 8 + kk) << 9) + lane * 8);
        f16x8 a1 = *(const f16x8*)(xs + (((size_t)(mt0 + 1) * 8 + kk) << 9) + lane * 8);
        f16x8 b0 = *(const f16x8*)(wtp + (((size_t)(48 + n16a + 0) * 8 + kk) << 9) + lane * 8);
        f16x8 b1 = *(const f16x8*)(wtp + (((size_t)(48 + n16a + 1) * 8 + kk) << 9) + lane * 8);
        acc[0][0] = __builtin_amdgcn_mfma_f32_16x16x32_f16(a0, b0, acc[0][0], 0, 0, 0);
        acc[0][1] = __builtin_amdgcn_mfma_f32_16x16x32_f16(a0, b1, acc[0][1], 0, 0, 0);
        acc[1][0] = __builtin_amdgcn_mfma_f32_16x16x32_f16(a1, b0, acc[1][0], 0, 0, 0);
        acc[1][1] = __builtin_amdgcn_mfma_f32_16x16x32_f16(a1, b1, acc[1][1], 0, 0, 0);
    }

#pragma unroll
    for (int i = 0; i < 2; ++i) {
        const int col = (n16a + i) * 16 + l16;
        const float bvv = bo[col];
#pragma unroll
        for (int jj = 0; jj < 2; ++jj) {
#pragma unroll
            for (int r = 0; r < 4; ++r) {
                const int row = (mt0 + jj) * 16 + quad * 4 + r;
                out[(size_t)row * 256 + col] = acc[jj][i][r] + bvv;
            }
        }
    }
}

// ---------------------------------------------------------------------------
// Flash attention: 256 blocks (XCD-swizzled: bh 0..63, qc 0..3), 4 waves,
// wave = 64 q-rows (2 y-tiles), 32 KV tiles, ZERO barriers, fixed-max softmax.
// tab C-init with y2 <- y1 register rotation (dy31_y2(kt) = dy31_y1(kt-1)).
// Epilogue: wave-private LDS transpose -> fragment-packed xs (A-layout for
// gemm_out).
// ---------------------------------------------------------------------------
__global__ __launch_bounds__(256)
void attn_kernel(const _Float16* __restrict__ qs, const _Float16* __restrict__ ks,
                 const _Float16* __restrict__ vs, const float* __restrict__ tab,
                 _Float16* __restrict__ xs) {
    __shared__ __align__(16) _Float16 Ps[4][64][40];   // 20.5 KB

    const int tid  = threadIdx.x;
    const int w    = tid >> 6;
    const int lane = tid & 63;
    const int quad = lane >> 4;
    const int l16  = lane & 15;

    const int n     = blockIdx.x;
    const int xcd   = n & 7;
    const int local = n >> 3;              // 0..31
    const int bh    = xcd * 8 + (local & 7);
    const int qc    = local >> 3;          // 0..3
    const int b = bh >> 3, h = bh & 7;
    const int y1 = qc * 8 + w * 2;         // first y-tile (0..30, even)

    // Q frags: 4 x 16q (2 y-tiles x 2 subs)
    const _Float16* qbase = qs + (((size_t)(bh * 32 + y1) * 2) << 9) + lane * 8;
    f16x8 qf[4];
    qf[0] = *(const f16x8*)(qbase);
    qf[1] = *(const f16x8*)(qbase + 512);
    qf[2] = *(const f16x8*)(qbase + 1024);
    qf[3] = *(const f16x8*)(qbase + 1536);

    const _Float16* kp = ks + (((size_t)bh * 64) << 9) + lane * 8;
    const _Float16* vp = vs + (((size_t)bh * 64) << 9) + lane * 8;
    const float* tb = tab + (((size_t)h * 189) << 8) + lane * 4;

    f16x8 ones;
#pragma unroll
    for (int j = 0; j < 8; ++j) ones[j] = (_Float16)1.0f;

    f32x4 o[2][4], ol[4];
#pragma unroll
    for (int j = 0; j < 4; ++j) {
        o[0][j] = (f32x4){0.f, 0.f, 0.f, 0.f};
        o[1][j] = (f32x4){0.f, 0.f, 0.f, 0.f};
        ol[j]   = (f32x4){0.f, 0.f, 0.f, 0.f};
    }

    f16x8 kf0 = *(const f16x8*)(kp);
    f16x8 kf1 = *(const f16x8*)(kp + 512);
    f16x8 vf0 = *(const f16x8*)(vp);
    f16x8 vf1 = *(const f16x8*)(vp + 512);
    f32x4 cy1[3], cy2[3];
#pragma unroll
    for (int e = 0; e < 3; ++e) {
        cy1[e] = *(const f32x4*)(tb + (((y1 + 31) * 3 + e) << 8));
        cy2[e] = *(const f32x4*)(tb + (((y1 + 32) * 3 + e) << 8));
    }

#pragma unroll 2
    for (int kt = 0; kt < 32; ++kt) {
        const bool more = (kt < 31);
        f16x8 nk0, nk1, nv0, nv1;
        f32x4 nc[3];
        if (more) {
            const _Float16* kq = kp + (kt + 1) * 1024;
            nk0 = *(const f16x8*)(kq);
            nk1 = *(const f16x8*)(kq + 512);
            const _Float16* vq = vp + (kt + 1) * 1024;
            nv0 = *(const f16x8*)(vq);
            nv1 = *(const f16x8*)(vq + 512);
            const int d = (y1 + 30 - kt) * 3;
#pragma unroll
            for (int e = 0; e < 3; ++e) nc[e] = *(const f32x4*)(tb + ((d + e) << 8));
        }

        // S^T = K.Q^T + bias (C-init); rows=keys, cols=q. e = (j&1) - i + 1.
        f32x4 s;
        f16x4 p;
        _Float16* pw;
#pragma unroll
        for (int j = 0; j < 4; ++j) {
            const f32x4* cy = (j < 2) ? cy1 : cy2;
            pw = &Ps[w][16 * j + l16][quad * 4];
            s = __builtin_amdgcn_mfma_f32_16x16x32_f16(kf0, qf[j], cy[(j & 1) + 1], 0, 0, 0);
#pragma unroll
            for (int r = 0; r < 4; ++r) p[r] = (_Float16)__builtin_amdgcn_exp2f(s[r]);
            *(f16x4*)(pw) = p;
            s = __builtin_amdgcn_mfma_f32_16x16x32_f16(kf1, qf[j], cy[(j & 1)], 0, 0, 0);
#pragma unroll
            for (int r = 0; r < 4; ++r) p[r] = (_Float16)__builtin_amdgcn_exp2f(s[r]);
            *(f16x4*)(pw + 16) = p;
        }

        // PV + row sums
#pragma unroll
        for (int j = 0; j < 4; ++j) {
            const f16x8 pf = *(const f16x8*)(&Ps[w][16 * j + l16][quad * 8]);
            o[0][j] = __builtin_amdgcn_mfma_f32_16x16x32_f16(vf0, pf, o[0][j], 0, 0, 0);
            o[1][j] = __builtin_amdgcn_mfma_f32_16x16x32_f16(vf1, pf, o[1][j], 0, 0, 0);
            ol[j]   = __builtin_amdgcn_mfma_f32_16x16x32_f16(ones, pf, ol[j], 0, 0, 0);
        }

        if (more) {
            kf0 = nk0; kf1 = nk1; vf0 = nv0; vf1 = nv1;
#pragma unroll
            for (int e = 0; e < 3; ++e) { cy2[e] = cy1[e]; cy1[e] = nc[e]; }
        }
    }

    // epilogue: normalize, transpose via wave-private LDS, packed store to xs
#pragma unroll
    for (int j = 0; j < 4; ++j) {
        const float inv = __builtin_amdgcn_rcpf(ol[j][0]);
#pragma unroll
        for (int i = 0; i < 2; ++i) {
            f16x4 pk;
#pragma unroll
            for (int r = 0; r < 4; ++r) pk[r] = (_Float16)(o[i][j][r] * inv);
            *(f16x4*)(&Ps[w][16 * j + l16][16 * i + quad * 4]) = pk;
        }
    }
    const int mt0 = b * 64 + qc * 16 + w * 4;
#pragma unroll
    for (int s4 = 0; s4 < 4; ++s4) {
        f16x8 af = *(const f16x8*)(&Ps[w][16 * s4 + l16][quad * 8]);
        *(f16x8*)(xs + (((size_t)(mt0 + s4) * 8 + h) << 9) + lane * 8) = af;
    }
}

// ---------------------------------------------------------------------------
extern "C" void kernel_launch(void* const* d_in, const int* in_sizes, int n_in,
                              void* d_out, int out_size, void* d_ws, size_t ws_size,
                              hipStream_t stream) {
    const float* in_q  = (const float*)d_in[0];
    const float* in_kv = (const float*)d_in[1];
    const float* Wq    = (const float*)d_in[2];
    const float* bq    = (const float*)d_in[3];
    const float* Wk    = (const float*)d_in[4];
    const float* bk    = (const float*)d_in[5];
    const float* Wv    = (const float*)d_in[6];
    const float* bv    = (const float*)d_in[7];
    const float* rel   = (const float*)d_in[8];
    const float* Wo    = (const float*)d_in[9];
    const float* bo    = (const float*)d_in[10];
    float* out = (float*)d_out;

    char* wsb = (char*)d_ws;
    _Float16* qs  = (_Float16*)(wsb);                         // 4 MB packed Q
    _Float16* ks  = (_Float16*)(wsb + (size_t)4  * 1048576);  // 4 MB packed K
    _Float16* vs  = (_Float16*)(wsb + (size_t)8  * 1048576);  // 4 MB packed V^T
    _Float16* xs  = (_Float16*)(wsb + (size_t)12 * 1048576);  // 4 MB packed X
    _Float16* wtp = (_Float16*)(wsb + (size_t)16 * 1048576);  // 512 KB packed W
    float*    tab = (float*)   (wsb + (size_t)17 * 1048576);  // 1.55 MB bias tab

    const dim3 blk(256);

    prep_kernel<<<dim3(95), blk, 0, stream>>>(Wq, Wk, Wv, Wo, rel, wtp, tab);
    gemm_qkv_kernel<<<dim3(128, 2), blk, 0, stream>>>(
        in_q, in_kv, wtp, bq, bk, bv, qs, ks, vs);
    attn_kernel<<<dim3(256), blk, 0, stream>>>(qs, ks, vs, tab, xs);
    gemm_out_kernel<<<dim3(128, 4), blk, 0, stream>>>(xs, wtp, bo, out);
}

// Round 8
// 127.340 us; speedup vs baseline: 1.0129x; 1.0129x over previous
//
#include <hip/hip_runtime.h>

// Problem constants
#define B_SZ   8
#define S_LEN  1024
#define D_MOD  256
#define NHEADS 8
#define LOG2E  1.4426950408889634f
#define QSCALE_LOG2E 0.2550352766751165f   // (1/sqrt(32)) * log2(e)

typedef _Float16 f16x8 __attribute__((ext_vector_type(8)));
typedef _Float16 f16x4 __attribute__((ext_vector_type(4)));
typedef float    f32x4 __attribute__((ext_vector_type(4)));

// ---------------------------------------------------------------------------
// prep: blocks 0..31  : pack 4 fp32 W mats -> fragment-ordered fp16 wtp.
//        wtp[((mat*16+n16)*8+kk)*512 + lane*8 + j]
//          = W[kk*32 + (lane>>4)*8 + j][n16*16 + (lane&15)]
//       blocks 32..94 : fp16 bias C-init table
//        tabh[((h*63+dy31)*3+e)*256 + lane*4 + r]
//          = rel[(dy31*63 + 16e + l16 - quad*4 - r + 15)*8 + h] * LOG2E
// ---------------------------------------------------------------------------
__global__ __launch_bounds__(256)
void prep_kernel(const float* __restrict__ Wq, const float* __restrict__ Wk,
                 const float* __restrict__ Wv, const float* __restrict__ Wo,
                 const float* __restrict__ rel,
                 _Float16* __restrict__ wtp, _Float16* __restrict__ tabh) {
    if (blockIdx.x < 32) {
        __shared__ _Float16 Wl[32 * 264];
        const int mi = blockIdx.x >> 3;
        const int k0 = (blockIdx.x & 7) << 5;
        const float* W = (mi == 0) ? Wq : (mi == 1) ? Wk : (mi == 2) ? Wv : Wo;
        {
            const int r  = threadIdx.x >> 3;
            const int c4 = (threadIdx.x & 7) * 4;
            const float* src = W + (size_t)(k0 + r) * 256 + c4;
#pragma unroll
            for (int g = 0; g < 8; ++g) {
                f32x4 v = *(const f32x4*)(src + g * 32);
                f16x4 o;
#pragma unroll
                for (int j = 0; j < 4; ++j) o[j] = (_Float16)v[j];
                *(f16x4*)(&Wl[r * 264 + c4 + g * 32]) = o;
            }
        }
        __syncthreads();
        const int n16 = threadIdx.x >> 4;
        const int l16 = threadIdx.x & 15;
        const int kk  = k0 >> 5;
#pragma unroll
        for (int quad = 0; quad < 4; ++quad) {
            f16x8 v;
#pragma unroll
            for (int j = 0; j < 8; ++j) v[j] = Wl[(quad * 8 + j) * 264 + n16 * 16 + l16];
            *(f16x8*)(wtp + (((size_t)(mi * 16 + n16) * 8 + kk) << 9) + (quad * 16 + l16) * 8) = v;
        }
        return;
    }
    __shared__ float rl[63 * 8];
    const int dy31 = blockIdx.x - 32;
    for (int f = threadIdx.x; f < 504; f += 256) rl[f] = rel[(size_t)dy31 * 504 + f];
    __syncthreads();
    const int h  = threadIdx.x >> 5;
    const int r5 = threadIdx.x & 31;
#pragma unroll
    for (int c = 0; c < 6; ++c) {
        const int oi   = r5 * 6 + c;       // 0..191
        const int e    = oi >> 6;
        const int lane = oi & 63;
        const int quad = lane >> 4, l16 = lane & 15;
        f16x4 v;
#pragma unroll
        for (int reg = 0; reg < 4; ++reg) {
            const int idx = 16 * e + l16 - quad * 4 - reg + 15;   // in [0,62]
            v[reg] = (_Float16)(rl[idx * 8 + h] * LOG2E);
        }
        *(f16x4*)(tabh + (((size_t)(h * 63 + dy31) * 3 + e) << 8) + lane * 4) = v;
    }
}

// ---------------------------------------------------------------------------
// QKV GEMM, balanced: grid (256, 3) = 768 equal blocks (3/CU).
// Block = 32 act-rows x full N=256, one matrix z in {Q, K, V}.
// A staged once to LDS (coalesced); B streamed from frag-packed wtp.
// Q/K use swapped MFMA operands (D[m=hd][n=act]); V normal (D[m=key][n=hd]).
// Epilogue: LDS transpose round-trip -> fragment-packed qs/ks/vs.
// ---------------------------------------------------------------------------
__global__ __launch_bounds__(256)
void gemm_qkv_kernel(const float* __restrict__ in_q, const float* __restrict__ in_kv,
                     const _Float16* __restrict__ wtp,
                     const float* __restrict__ bq, const float* __restrict__ bk,
                     const float* __restrict__ bv,
                     _Float16* __restrict__ qs, _Float16* __restrict__ ks,
                     _Float16* __restrict__ vs) {
    __shared__ __align__(16) _Float16 Lds[256 * 40];   // 20.5 KB, reused 3 ways
    const int tid  = threadIdx.x;
    const int w    = tid >> 6;
    const int lane = tid & 63;
    const int quad = lane >> 4;
    const int l16  = lane & 15;
    const int mt = blockIdx.x;         // 32-row tile, 0..255
    const int z  = blockIdx.y;         // 0=Q, 1=K, 2=V
    const int m0 = mt * 32;
    const int b  = mt >> 5, t = mt & 31;

    // stage A tile 32x256 fp32 -> fp16 (stride 264)
    {
        const int r  = tid >> 3;
        const int c4 = (tid & 7) * 4;
        const float* src = (z ? in_kv : in_q) + (size_t)(m0 + r) * 256 + c4;
        _Float16* dst = Lds + r * 264 + c4;
#pragma unroll
        for (int g = 0; g < 8; ++g) {
            f32x4 v = *(const f32x4*)(src + g * 32);
            f16x4 o;
#pragma unroll
            for (int j = 0; j < 4; ++j) o[j] = (_Float16)v[j];
            *(f16x4*)(dst + g * 32) = o;
        }
    }
    __syncthreads();

    f32x4 acc[2][4];
#pragma unroll
    for (int jj = 0; jj < 2; ++jj)
#pragma unroll
        for (int i = 0; i < 4; ++i) acc[jj][i] = (f32x4){0.f, 0.f, 0.f, 0.f};

#pragma unroll
    for (int kk = 0; kk < 8; ++kk) {
        const int k8 = kk * 32 + quad * 8;
        f16x8 a0 = *(const f16x8*)(Lds + l16 * 264 + k8);
        f16x8 a1 = *(const f16x8*)(Lds + (16 + l16) * 264 + k8);
#pragma unroll
        for (int i = 0; i < 4; ++i) {
            f16x8 wv = *(const f16x8*)(wtp + (((size_t)(z * 16 + w * 4 + i) * 8 + kk) << 9) + lane * 8);
            if (z < 2) {
                acc[0][i] = __builtin_amdgcn_mfma_f32_16x16x32_f16(wv, a0, acc[0][i], 0, 0, 0);
                acc[1][i] = __builtin_amdgcn_mfma_f32_16x16x32_f16(wv, a1, acc[1][i], 0, 0, 0);
            } else {
                acc[0][i] = __builtin_amdgcn_mfma_f32_16x16x32_f16(a0, wv, acc[0][i], 0, 0, 0);
                acc[1][i] = __builtin_amdgcn_mfma_f32_16x16x32_f16(a1, wv, acc[1][i], 0, 0, 0);
            }
        }
    }
    __syncthreads();   // LDS reuse

    if (z < 2) {
        // Ta[act 32][hd 256] stride 264: D^T with bias + scale
        const float* bias = z ? bk : bq;
        const float  sc   = z ? 1.0f : QSCALE_LOG2E;
#pragma unroll
        for (int i = 0; i < 4; ++i) {
            f32x4 b4 = *(const f32x4*)(bias + (w * 4 + i) * 16 + quad * 4);
#pragma unroll
            for (int jj = 0; jj < 2; ++jj) {
                f16x4 pk;
#pragma unroll
                for (int r = 0; r < 4; ++r) pk[r] = (_Float16)((acc[jj][i][r] + b4[r]) * sc);
                *(f16x4*)(Lds + (jj * 16 + l16) * 264 + (w * 4 + i) * 16 + quad * 4) = pk;
            }
        }
        __syncthreads();
        _Float16* dst = z ? ks : qs;
#pragma unroll
        for (int c = 0; c < 4; ++c) {
            const int sg = w * 4 + c;          // 0..15
            const int sub = sg >> 3, h = sg & 7;
            f16x8 v = *(const f16x8*)(Lds + (sub * 16 + l16) * 264 + h * 32 + quad * 8);
            *(f16x8*)(dst + (((size_t)((b * 8 + h) * 32 + t) * 2 + sub) << 9) + lane * 8) = v;
        }
    } else {
        // Tb[hd 256][key 32] stride 40: V^T with bias
#pragma unroll
        for (int i = 0; i < 4; ++i) {
            const float bvv = bv[(w * 4 + i) * 16 + l16];
#pragma unroll
            for (int jj = 0; jj < 2; ++jj) {
                f16x4 pk;
#pragma unroll
                for (int r = 0; r < 4; ++r) pk[r] = (_Float16)(acc[jj][i][r] + bvv);
                *(f16x4*)(Lds + ((w * 4 + i) * 16 + l16) * 40 + jj * 16 + quad * 4) = pk;
            }
        }
        __syncthreads();
#pragma unroll
        for (int c = 0; c < 4; ++c) {
            const int sg = w * 4 + c;
            const int sub = sg >> 3, h = sg & 7;
            f16x8 v = *(const f16x8*)(Lds + (h * 32 + sub * 16 + l16) * 40 + quad * 8);
            *(f16x8*)(vs + (((size_t)((b * 8 + h) * 32 + t) * 2 + sub) << 9) + lane * 8) = v;
        }
    }
}

// ---------------------------------------------------------------------------
// Output GEMM: zero-LDS, zero-barrier. A = xs (frag-packed by attn),
// B = wtp[mat 3] frag-packed stream. 512 blocks.
// ---------------------------------------------------------------------------
__global__ __launch_bounds__(256)
void gemm_out_kernel(const _Float16* __restrict__ xs, const _Float16* __restrict__ wtp,
                     const float* __restrict__ bo, float* __restrict__ out) {
    const int tid  = threadIdx.x;
    const int w    = tid >> 6;
    const int lane = tid & 63;
    const int quad = lane >> 4;
    const int l16  = lane & 15;
    const int bx = blockIdx.x, by = blockIdx.y;
    const int mt0  = bx * 4 + (w & 1) * 2;
    const int n16a = by * 4 + (w >> 1) * 2;

    f32x4 acc[2][2];
#pragma unroll
    for (int i = 0; i < 2; ++i)
#pragma unroll
        for (int j = 0; j < 2; ++j) acc[i][j] = (f32x4){0.f, 0.f, 0.f, 0.f};

#pragma unroll
    for (int kk = 0; kk < 8; ++kk) {
        f16x8 a0 = *(const f16x8*)(xs + (((size_t)(mt0 + 0) * 8 + kk) << 9) + lane * 8);
        f16x8 a1 = *(const f16x8*)(xs + (((size_t)(mt0 + 1) * 8 + kk) << 9) + lane * 8);
        f16x8 b0 = *(const f16x8*)(wtp + (((size_t)(48 + n16a + 0) * 8 + kk) << 9) + lane * 8);
        f16x8 b1 = *(const f16x8*)(wtp + (((size_t)(48 + n16a + 1) * 8 + kk) << 9) + lane * 8);
        acc[0][0] = __builtin_amdgcn_mfma_f32_16x16x32_f16(a0, b0, acc[0][0], 0, 0, 0);
        acc[0][1] = __builtin_amdgcn_mfma_f32_16x16x32_f16(a0, b1, acc[0][1], 0, 0, 0);
        acc[1][0] = __builtin_amdgcn_mfma_f32_16x16x32_f16(a1, b0, acc[1][0], 0, 0, 0);
        acc[1][1] = __builtin_amdgcn_mfma_f32_16x16x32_f16(a1, b1, acc[1][1], 0, 0, 0);
    }

#pragma unroll
    for (int i = 0; i < 2; ++i) {
        const int col = (n16a + i) * 16 + l16;
        const float bvv = bo[col];
#pragma unroll
        for (int jj = 0; jj < 2; ++jj) {
#pragma unroll
            for (int r = 0; r < 4; ++r) {
                const int row = (mt0 + jj) * 16 + quad * 4 + r;
                out[(size_t)row * 256 + col] = acc[jj][i][r] + bvv;
            }
        }
    }
}

// ---------------------------------------------------------------------------
// Flash attention (R6 core): 512 blocks (XCD-swizzled: bh, qc 0..7), 4 waves,
// wave = 32 q-rows, 32 KV tiles, ZERO barriers, fixed-max softmax.
// fp16 tab C-init (converted at use), ones-MFMA row sums, wave-private P
// round-trip. Epilogue: packed xs (A-layout for gemm_out) via LDS transpose.
// ---------------------------------------------------------------------------
__global__ __launch_bounds__(256)
void attn_kernel(const _Float16* __restrict__ qs, const _Float16* __restrict__ ks,
                 const _Float16* __restrict__ vs, const _Float16* __restrict__ tabh,
                 _Float16* __restrict__ xs) {
    __shared__ __align__(16) _Float16 Ps[4][32][40];

    const int tid  = threadIdx.x;
    const int w    = tid >> 6;
    const int lane = tid & 63;
    const int quad = lane >> 4;
    const int l16  = lane & 15;

    const int n     = blockIdx.x;
    const int xcd   = n & 7;
    const int local = n >> 3;
    const int bh    = xcd * 8 + (local & 7);
    const int qc    = local >> 3;          // 0..7
    const int b = bh >> 3, h = bh & 7;
    const int qrow_base = qc * 128 + w * 32;
    const int yq = qc * 4 + w;             // q y-tile 0..31

    const _Float16* qp = qs + (((size_t)(bh * 32 + yq) * 2) << 9) + lane * 8;
    const f16x8 qf0 = *(const f16x8*)(qp);
    const f16x8 qf1 = *(const f16x8*)(qp + 512);
    const _Float16* kp = ks + (((size_t)bh * 64) << 9) + lane * 8;   // +kt*1024
    const _Float16* vp = vs + (((size_t)bh * 64) << 9) + lane * 8;
    const _Float16* tb = tabh + (((size_t)h * 189) << 8) + lane * 4;

    f16x8 ones;
#pragma unroll
    for (int j = 0; j < 8; ++j) ones[j] = (_Float16)1.0f;

    f32x4 o00 = {0.f,0.f,0.f,0.f}, o01 = {0.f,0.f,0.f,0.f};
    f32x4 o10 = {0.f,0.f,0.f,0.f}, o11 = {0.f,0.f,0.f,0.f};
    f32x4 ol0 = {0.f,0.f,0.f,0.f}, ol1 = {0.f,0.f,0.f,0.f};

    f16x8 kf0 = *(const f16x8*)(kp);
    f16x8 kf1 = *(const f16x8*)(kp + 512);
    f16x8 vf0 = *(const f16x8*)(vp);
    f16x8 vf1 = *(const f16x8*)(vp + 512);
    f32x4 c0, c1, c2;
    {
        f16x4 t0 = *(const f16x4*)(tb + (((yq + 31) * 3 + 0) << 8));
        f16x4 t1 = *(const f16x4*)(tb + (((yq + 31) * 3 + 1) << 8));
        f16x4 t2 = *(const f16x4*)(tb + (((yq + 31) * 3 + 2) << 8));
#pragma unroll
        for (int r = 0; r < 4; ++r) {
            c0[r] = (float)t0[r]; c1[r] = (float)t1[r]; c2[r] = (float)t2[r];
        }
    }

    for (int kt = 0; kt < 32; ++kt) {
        const bool more = (kt < 31);
        f16x8 nk0, nk1, nv0, nv1;
        f16x4 nt0, nt1, nt2;
        if (more) {
            const _Float16* kq = kp + (kt + 1) * 1024;
            nk0 = *(const f16x8*)(kq);
            nk1 = *(const f16x8*)(kq + 512);
            const _Float16* vq = vp + (kt + 1) * 1024;
            nv0 = *(const f16x8*)(vq);
            nv1 = *(const f16x8*)(vq + 512);
            const int d = (yq + 30 - kt) * 3;
            nt0 = *(const f16x4*)(tb + ((d + 0) << 8));
            nt1 = *(const f16x4*)(tb + ((d + 1) << 8));
            nt2 = *(const f16x4*)(tb + ((d + 2) << 8));
        }

        // S^T = K.Q^T + bias (C-init); rows=keys, cols=q
        f32x4 s00 = __builtin_amdgcn_mfma_f32_16x16x32_f16(kf0, qf0, c1, 0, 0, 0);
        f32x4 s01 = __builtin_amdgcn_mfma_f32_16x16x32_f16(kf1, qf0, c0, 0, 0, 0);
        f32x4 s10 = __builtin_amdgcn_mfma_f32_16x16x32_f16(kf0, qf1, c2, 0, 0, 0);
        f32x4 s11 = __builtin_amdgcn_mfma_f32_16x16x32_f16(kf1, qf1, c1, 0, 0, 0);

        f16x4 p;
#pragma unroll
        for (int r = 0; r < 4; ++r) p[r] = (_Float16)__builtin_amdgcn_exp2f(s00[r]);
        *(f16x4*)(&Ps[w][l16][quad * 4]) = p;
#pragma unroll
        for (int r = 0; r < 4; ++r) p[r] = (_Float16)__builtin_amdgcn_exp2f(s01[r]);
        *(f16x4*)(&Ps[w][l16][16 + quad * 4]) = p;
#pragma unroll
        for (int r = 0; r < 4; ++r) p[r] = (_Float16)__builtin_amdgcn_exp2f(s10[r]);
        *(f16x4*)(&Ps[w][16 + l16][quad * 4]) = p;
#pragma unroll
        for (int r = 0; r < 4; ++r) p[r] = (_Float16)__builtin_amdgcn_exp2f(s11[r]);
        *(f16x4*)(&Ps[w][16 + l16][16 + quad * 4]) = p;

        const f16x8 pf0 = *(const f16x8*)(&Ps[w][l16][quad * 8]);
        const f16x8 pf1 = *(const f16x8*)(&Ps[w][16 + l16][quad * 8]);
        o00 = __builtin_amdgcn_mfma_f32_16x16x32_f16(vf0, pf0, o00, 0, 0, 0);
        o01 = __builtin_amdgcn_mfma_f32_16x16x32_f16(vf0, pf1, o01, 0, 0, 0);
        o10 = __builtin_amdgcn_mfma_f32_16x16x32_f16(vf1, pf0, o10, 0, 0, 0);
        o11 = __builtin_amdgcn_mfma_f32_16x16x32_f16(vf1, pf1, o11, 0, 0, 0);
        ol0 = __builtin_amdgcn_mfma_f32_16x16x32_f16(ones, pf0, ol0, 0, 0, 0);
        ol1 = __builtin_amdgcn_mfma_f32_16x16x32_f16(ones, pf1, ol1, 0, 0, 0);

        if (more) {
            kf0 = nk0; kf1 = nk1; vf0 = nv0; vf1 = nv1;
#pragma unroll
            for (int r = 0; r < 4; ++r) {
                c0[r] = (float)nt0[r]; c1[r] = (float)nt1[r]; c2[r] = (float)nt2[r];
            }
        }
    }

    // epilogue: normalize, wave-private LDS transpose, packed xs store
#pragma unroll
    for (int qsub = 0; qsub < 2; ++qsub) {
        const f32x4 olo = qsub ? o01 : o00;   // hd 0-15
        const f32x4 ohi = qsub ? o11 : o10;   // hd 16-31
        const f32x4 ll  = qsub ? ol1 : ol0;
        const float inv = __builtin_amdgcn_rcpf(ll[0]);
        f16x4 u, v;
#pragma unroll
        for (int r = 0; r < 4; ++r) {
            u[r] = (_Float16)(olo[r] * inv);
            v[r] = (_Float16)(ohi[r] * inv);
        }
        *(f16x4*)(&Ps[w][qsub * 16 + l16][quad * 4]) = u;
        *(f16x4*)(&Ps[w][qsub * 16 + l16][16 + quad * 4]) = v;
    }
#pragma unroll
    for (int qsub = 0; qsub < 2; ++qsub) {
        f16x8 af = *(const f16x8*)(&Ps[w][qsub * 16 + l16][quad * 8]);
        const int mtile = b * 64 + qc * 8 + w * 2 + qsub;
        *(f16x8*)(xs + (((size_t)mtile * 8 + h) << 9) + lane * 8) = af;
    }
}

// ---------------------------------------------------------------------------
extern "C" void kernel_launch(void* const* d_in, const int* in_sizes, int n_in,
                              void* d_out, int out_size, void* d_ws, size_t ws_size,
                              hipStream_t stream) {
    const float* in_q  = (const float*)d_in[0];
    const float* in_kv = (const float*)d_in[1];
    const float* Wq    = (const float*)d_in[2];
    const float* bq    = (const float*)d_in[3];
    const float* Wk    = (const float*)d_in[4];
    const float* bk    = (const float*)d_in[5];
    const float* Wv    = (const float*)d_in[6];
    const float* bv    = (const float*)d_in[7];
    const float* rel   = (const float*)d_in[8];
    const float* Wo    = (const float*)d_in[9];
    const float* bo    = (const float*)d_in[10];
    float* out = (float*)d_out;

    char* wsb = (char*)d_ws;
    _Float16* qs   = (_Float16*)(wsb);                         // 4 MB packed Q
    _Float16* ks   = (_Float16*)(wsb + (size_t)4  * 1048576);  // 4 MB packed K
    _Float16* vs   = (_Float16*)(wsb + (size_t)8  * 1048576);  // 4 MB packed V^T
    _Float16* xs   = (_Float16*)(wsb + (size_t)12 * 1048576);  // 4 MB packed X
    _Float16* wtp  = (_Float16*)(wsb + (size_t)16 * 1048576);  // 512 KB packed W
    _Float16* tabh = (_Float16*)(wsb + (size_t)17 * 1048576);  // 774 KB fp16 tab

    const dim3 blk(256);

    prep_kernel<<<dim3(95), blk, 0, stream>>>(Wq, Wk, Wv, Wo, rel, wtp, tabh);
    gemm_qkv_kernel<<<dim3(256, 3), blk, 0, stream>>>(
        in_q, in_kv, wtp, bq, bk, bv, qs, ks, vs);
    attn_kernel<<<dim3(512), blk, 0, stream>>>(qs, ks, vs, tabh, xs);
    gemm_out_kernel<<<dim3(128, 4), blk, 0, stream>>>(xs, wtp, bo, out);
}